// Round 4
// baseline (166.404 us; speedup 1.0000x reference)
//
#include <hip/hip_runtime.h>

// VectorQuantizer: x [32,64,64,64] f32, emb [512,64] f32 -> out [32,64,64,64] f32
// R14: revert R13's parallel-rescore machinery (regression: 4x rescore
// expansion + prefix/queue overhead + xt bank conflicts); back to R12's
// per-element detect + serial rescore. New: TWO-PASS MFMA screen to cut
// unified regs to <=64 (R12's s[4][4][4] was ~64 AGPRs -> 4 waves/SIMD cap):
//  - pass 1: stream efr tiles from L2 (8 transient regs), C-init from lesq
//    LDS, fold acc into mm4[mt][nt] (16 regs) immediately
//  - pass 2 (after global-threshold barrier): re-run MFMAs (deterministic ->
//    bit-identical acc), detect per-element vs tr, serial rescore (R12 body).
//    Tiles with !__any(mm4<tr) skip recompute (wave-uniform, exact).
//  - __launch_bounds__(512,8) pins allocator at 64 regs -> 32 waves/CU.
// Exact-score semantics unchanged from R8-R12 (absmax==0): sequential-c fmaf
// dot, pairwise-8 sums, _rn combine, lexicographic (se,k) u64 atomicMin.

#define KNUM 512
#define CDIM 64
#define MPB  64

typedef __attribute__((ext_vector_type(8))) short bf16x8;
typedef __attribute__((ext_vector_type(4))) float f32x4;

__device__ __forceinline__ unsigned f2bf(float f) {   // RNE f32->bf16
    unsigned u = __float_as_uint(f);
    return (u + 0x7FFFu + ((u >> 16) & 1u)) >> 16;
}
__device__ __forceinline__ unsigned ordf(float f) {   // total-order encode
    unsigned u = __float_as_uint(f);
    return u ^ ((unsigned)(((int)u) >> 31) | 0x80000000u);
}
__device__ __forceinline__ float ordinv(unsigned u) {
    unsigned fb = (u & 0x80000000u) ? (u ^ 0x80000000u) : ~u;
    return __uint_as_float(fb);
}

__device__ __forceinline__ float xsq_pairwise8(const float* xr)   // np order
{
    float r[8];
    {
        const float4 a = *(const float4*)&xr[0];
        const float4 c = *(const float4*)&xr[4];
        r[0] = __fmul_rn(a.x, a.x); r[1] = __fmul_rn(a.y, a.y);
        r[2] = __fmul_rn(a.z, a.z); r[3] = __fmul_rn(a.w, a.w);
        r[4] = __fmul_rn(c.x, c.x); r[5] = __fmul_rn(c.y, c.y);
        r[6] = __fmul_rn(c.z, c.z); r[7] = __fmul_rn(c.w, c.w);
    }
    #pragma unroll
    for (int i = 1; i < 8; ++i) {
        const float4 a = *(const float4*)&xr[8 * i];
        const float4 c = *(const float4*)&xr[8 * i + 4];
        r[0] = __fadd_rn(r[0], __fmul_rn(a.x, a.x));
        r[1] = __fadd_rn(r[1], __fmul_rn(a.y, a.y));
        r[2] = __fadd_rn(r[2], __fmul_rn(a.z, a.z));
        r[3] = __fadd_rn(r[3], __fmul_rn(a.w, a.w));
        r[4] = __fadd_rn(r[4], __fmul_rn(c.x, c.x));
        r[5] = __fadd_rn(r[5], __fmul_rn(c.y, c.y));
        r[6] = __fadd_rn(r[6], __fmul_rn(c.z, c.z));
        r[7] = __fadd_rn(r[7], __fmul_rn(c.w, c.w));
    }
    return __fadd_rn(
        __fadd_rn(__fadd_rn(r[0], r[1]), __fadd_rn(r[2], r[3])),
        __fadd_rn(__fadd_rn(r[4], r[5]), __fadd_rn(r[6], r[7])));
}

__global__ __launch_bounds__(64) void vq_prep(const float* __restrict__ emb,
                                              float* __restrict__ e_sq,
                                              unsigned* __restrict__ ebf)
{
    const int k = blockIdx.x * 64 + threadIdx.x;
    const float* e = emb + k * CDIM;
    float4 f[16];
    #pragma unroll
    for (int i = 0; i < 16; ++i) f[i] = ((const float4*)e)[i];

    float r[8];
    r[0] = __fmul_rn(f[0].x, f[0].x); r[1] = __fmul_rn(f[0].y, f[0].y);
    r[2] = __fmul_rn(f[0].z, f[0].z); r[3] = __fmul_rn(f[0].w, f[0].w);
    r[4] = __fmul_rn(f[1].x, f[1].x); r[5] = __fmul_rn(f[1].y, f[1].y);
    r[6] = __fmul_rn(f[1].z, f[1].z); r[7] = __fmul_rn(f[1].w, f[1].w);
    #pragma unroll
    for (int i = 1; i < 8; ++i) {
        const float4 a = f[2 * i], c = f[2 * i + 1];
        r[0] = __fadd_rn(r[0], __fmul_rn(a.x, a.x));
        r[1] = __fadd_rn(r[1], __fmul_rn(a.y, a.y));
        r[2] = __fadd_rn(r[2], __fmul_rn(a.z, a.z));
        r[3] = __fadd_rn(r[3], __fmul_rn(a.w, a.w));
        r[4] = __fadd_rn(r[4], __fmul_rn(c.x, c.x));
        r[5] = __fadd_rn(r[5], __fmul_rn(c.y, c.y));
        r[6] = __fadd_rn(r[6], __fmul_rn(c.z, c.z));
        r[7] = __fadd_rn(r[7], __fmul_rn(c.w, c.w));
    }
    e_sq[k] = __fadd_rn(
        __fadd_rn(__fadd_rn(r[0], r[1]), __fadd_rn(r[2], r[3])),
        __fadd_rn(__fadd_rn(r[4], r[5]), __fadd_rn(r[6], r[7])));

    // bf16(-2e): exact power-of-2 scale, products are exactly -2x original
    unsigned buf[32];
    #pragma unroll
    for (int i = 0; i < 16; ++i) {
        buf[2 * i]     = f2bf(__fmul_rn(-2.0f, f[i].x))
                       | (f2bf(__fmul_rn(-2.0f, f[i].y)) << 16);
        buf[2 * i + 1] = f2bf(__fmul_rn(-2.0f, f[i].z))
                       | (f2bf(__fmul_rn(-2.0f, f[i].w)) << 16);
    }
    uint4* dst = (uint4*)(ebf + k * 32);
    #pragma unroll
    for (int i = 0; i < 8; ++i) dst[i] = ((const uint4*)buf)[i];
}

__global__ __launch_bounds__(512, 8) void vq_main(const float* __restrict__ x,
                                                  const float* __restrict__ emb,
                                                  const float* __restrict__ e_sq,
                                                  const unsigned* __restrict__ ebf,
                                                  float* __restrict__ out)
{
    __shared__ float    xt[MPB][68];           // 17408 B exact x
    __shared__ _Float16 xbf[MPB][72];          //  9216 B bf16 x (B-frags)
    __shared__ float    axp[MPB][10];          //  2560 B |x| partials
    __shared__ float    margl[MPB];            //   256 B per-pixel margin
    __shared__ float    xsql[MPB];             //   256 B per-pixel ||x||^2
    __shared__ float    lesq[KNUM];            //  2048 B e_sq copy
    __shared__ unsigned pthr[MPB];             //   256 B ordered screen min
    __shared__ unsigned long long bestpk[MPB]; //   512 B

    const int t    = threadIdx.x;
    const int pix0 = blockIdx.x * MPB;
    const int b    = pix0 >> 12;
    const int hw0  = pix0 & 4095;
    const float* xb = x + ((size_t)b << 18) + hw0;

    const int l    = t & 63;
    const int w    = __builtin_amdgcn_readfirstlane(t >> 6);  // uniform wave id
    const int i15  = l & 15, quad = l >> 4;
    const int nbase = w * 64;

    // ---- stage x (HBM/L3, longest latency first) ----
    {
        const float* xp = xb + ((size_t)(8 * w) << 12) + l;
        float v[8];
        #pragma unroll
        for (int j = 0; j < 8; ++j) v[j] = xp[(size_t)j << 12];

        lesq[t] = e_sq[t];                     // KNUM == blockDim
        if (t < MPB) { pthr[t] = 0xFFFFFFFFu; bestpk[t] = ~0ull; }

        *(float4*)&xt[l][8 * w]     = make_float4(v[0], v[1], v[2], v[3]);
        *(float4*)&xt[l][8 * w + 4] = make_float4(v[4], v[5], v[6], v[7]);
        uint4 dp;
        dp.x = f2bf(v[0]) | (f2bf(v[1]) << 16);
        dp.y = f2bf(v[2]) | (f2bf(v[3]) << 16);
        dp.z = f2bf(v[4]) | (f2bf(v[5]) << 16);
        dp.w = f2bf(v[6]) | (f2bf(v[7]) << 16);
        *(uint4*)&xbf[l][8 * w] = dp;
        axp[l][w] = ((fabsf(v[0]) + fabsf(v[1])) + (fabsf(v[2]) + fabsf(v[3])))
                  + ((fabsf(v[4]) + fabsf(v[5])) + (fabsf(v[6]) + fabsf(v[7])));
    }
    __syncthreads();                           // B1

    // ---- wave 0: per-pixel margin; waves 4-7: exact ||x||^2 ----
    if (t < MPB) {
        const float ax = ((axp[t][0] + axp[t][1]) + (axp[t][2] + axp[t][3]))
                       + ((axp[t][4] + axp[t][5]) + (axp[t][6] + axp[t][7]));
        margl[t] = fmaf(4.0e-5f, ax, 5.0e-4f);
    }
    if (w >= 4 && l < 16) {                    // 2-way bank alias = free
        const int p = (w - 4) * 16 + l;
        xsql[p] = xsq_pairwise8(xt[p]);
    }

    // ---- pass 1: MFMA screen, efr streamed from L2, keep cell mins only ----
    float mm4[4][4];                           // [mt][nt]
    #pragma unroll
    for (int mt = 0; mt < 4; ++mt) {
        const char* ep = (const char*)ebf
            + (size_t)(nbase + mt * 16 + i15) * 128 + quad * 16;
        const bf16x8 ef0 = *(const bf16x8*)(ep);
        const bf16x8 ef1 = *(const bf16x8*)(ep + 64);
        const f32x4 ci = *(const f32x4*)&lesq[nbase + mt * 16 + quad * 4];
        #pragma unroll
        for (int nt = 0; nt < 4; ++nt) {
            const bf16x8 xf0 = *(const bf16x8*)&xbf[nt * 16 + i15][quad * 8];
            const bf16x8 xf1 = *(const bf16x8*)&xbf[nt * 16 + i15][quad * 8 + 32];
            f32x4 acc = ci;                    // C-init = e_sq[code row]
            acc = __builtin_amdgcn_mfma_f32_16x16x32_bf16(ef0, xf0, acc, 0, 0, 0);
            acc = __builtin_amdgcn_mfma_f32_16x16x32_bf16(ef1, xf1, acc, 0, 0, 0);
            mm4[mt][nt] = fminf(fminf(acc[0], acc[1]), fminf(acc[2], acc[3]));
        }
    }
    // per-pixel min over this wave's 64 codes: 3 fmin + 2 shfl per nt
    #pragma unroll
    for (int nt = 0; nt < 4; ++nt) {
        float mv = fminf(fminf(mm4[0][nt], mm4[1][nt]),
                         fminf(mm4[2][nt], mm4[3][nt]));
        mv = fminf(mv, __shfl_xor(mv, 16));
        mv = fminf(mv, __shfl_xor(mv, 32));
        if (quad == 0) atomicMin(&pthr[nt * 16 + i15], ordf(mv));
    }
    __syncthreads();                           // B2

    // ---- pass 2: recompute gated tiles, per-element detect, serial rescore ----
    {
        float tr[4];
        #pragma unroll
        for (int nt = 0; nt < 4; ++nt)
            tr[nt] = __fadd_rn(ordinv(pthr[nt * 16 + i15]),
                               margl[nt * 16 + i15]);

        unsigned long long m = 0;
        #pragma unroll
        for (int mt = 0; mt < 4; ++mt) {
            // wave-uniform gate: any lane's cell min under threshold?
            bool any = false;
            #pragma unroll
            for (int nt = 0; nt < 4; ++nt)
                any = any || (mm4[mt][nt] < tr[nt]);
            if (!__any(any)) continue;

            const char* ep = (const char*)ebf
                + (size_t)(nbase + mt * 16 + i15) * 128 + quad * 16;
            const bf16x8 ef0 = *(const bf16x8*)(ep);
            const bf16x8 ef1 = *(const bf16x8*)(ep + 64);
            const f32x4 ci = *(const f32x4*)&lesq[nbase + mt * 16 + quad * 4];
            #pragma unroll
            for (int nt = 0; nt < 4; ++nt) {
                const bf16x8 xf0 = *(const bf16x8*)&xbf[nt * 16 + i15][quad * 8];
                const bf16x8 xf1 = *(const bf16x8*)&xbf[nt * 16 + i15][quad * 8 + 32];
                f32x4 acc = ci;                // bit-identical to pass 1
                acc = __builtin_amdgcn_mfma_f32_16x16x32_bf16(ef0, xf0, acc, 0, 0, 0);
                acc = __builtin_amdgcn_mfma_f32_16x16x32_bf16(ef1, xf1, acc, 0, 0, 0);
                #pragma unroll
                for (int r = 0; r < 4; ++r)
                    if (acc[r] < tr[nt])       // rare
                        m |= 1ull << (mt * 16 + nt * 4 + r);
            }
        }

        while (m) {                            // serial rescore (R12 body)
            const int bit = __builtin_ctzll(m);
            m &= m - 1;
            const int mt = bit >> 4, nt = (bit >> 2) & 3, r = bit & 3;
            const int p2 = nt * 16 + i15;                    // pixel
            const int k  = nbase + mt * 16 + quad * 4 + r;   // code
            const float xs = xsql[p2];
            const float* er = emb + (size_t)k * CDIM;
            float d = 0.f;
            #pragma unroll
            for (int c4 = 0; c4 < 16; ++c4) {  // sequential-c fmaf = np order
                const float4 xv = *(const float4*)&xt[p2][4 * c4];
                const float4 ev = *(const float4*)&er[4 * c4];
                d = fmaf(xv.x, ev.x, d);
                d = fmaf(xv.y, ev.y, d);
                d = fmaf(xv.z, ev.z, d);
                d = fmaf(xv.w, ev.w, d);
            }
            const float se = __fsub_rn(__fadd_rn(xs, lesq[k]),
                                       __fmul_rn(2.0f, d));
            const unsigned long long pkd =
                ((unsigned long long)ordf(se) << 32) | (unsigned)k;
            atomicMin(&bestpk[p2], pkd);       // lexicographic (se, k)
        }
    }
    __syncthreads();                           // B3

    // ---- gather winning emb row (bit-exact) -> [B,C,H,W] ----
    {
        const int wi = (int)(bestpk[l] & 0xFFFFu);
        const float* ew = emb + (size_t)wi * CDIM + 8 * w;
        const float4 e0 = *(const float4*)ew;
        const float4 e1 = *(const float4*)(ew + 4);
        float* ob = out + ((size_t)b << 18) + (((size_t)(8 * w)) << 12) + hw0 + l;
        ob[(size_t)0 << 12] = e0.x;
        ob[(size_t)1 << 12] = e0.y;
        ob[(size_t)2 << 12] = e0.z;
        ob[(size_t)3 << 12] = e0.w;
        ob[(size_t)4 << 12] = e1.x;
        ob[(size_t)5 << 12] = e1.y;
        ob[(size_t)6 << 12] = e1.z;
        ob[(size_t)7 << 12] = e1.w;
    }
}

extern "C" void kernel_launch(void* const* d_in, const int* in_sizes, int n_in,
                              void* d_out, int out_size, void* d_ws, size_t ws_size,
                              hipStream_t stream)
{
    const float* x   = (const float*)d_in[0];
    const float* emb = (const float*)d_in[1];
    float* out  = (float*)d_out;
    float*    e_sq = (float*)d_ws;                 // 2 KB
    unsigned* ebf  = (unsigned*)d_ws + KNUM;       // 64 KB bf16(-2e)

    hipLaunchKernelGGL(vq_prep, dim3(KNUM / 64), dim3(64), 0, stream, emb, e_sq, ebf);
    const int nblocks = (32 * 64 * 64) / MPB;      // 2048
    hipLaunchKernelGGL(vq_main, dim3(nblocks), dim3(512), 0, stream,
                       x, emb, e_sq, ebf, out);
}

// Round 5
// 156.385 us; speedup vs baseline: 1.0641x; 1.0641x over previous
//
#include <hip/hip_runtime.h>

// VectorQuantizer: x [32,64,64,64] f32, emb [512,64] f32 -> out [32,64,64,64] f32
// R15: R14's two-pass screen with the reg cap FIXED. R14's (512,8) pinned the
// allocator at 64 unified regs but the structure needs ~85 -> massive scratch
// spills (WRITE_SIZE 32->180 MB, 98 us). Occupancy DID rise to 72% -> regfile
// is the occupancy limiter; the right budget is (512,6) = 85 regs:
//   - fits the two-pass working set spill-free
//   - crosses the 3-blocks/CU threshold (512-thr blocks quantize at
//     <=128 regs -> 2 blk/CU, <=85 -> 3 blk/CU, <=64 -> 4 blk/CU unreachable)
// Structure unchanged from R14 (validated absmax==0):
//  - pass 1: stream ef tiles from L2, C-init from lesq LDS, fold acc into
//    mm4[mt][nt] immediately (no 64-float score array)
//  - pass 2: re-run MFMAs (deterministic -> bit-identical), per-element
//    detect vs margin threshold, serial exact rescore (R12 body); tiles with
//    !__any(mm4<tr) skip recompute (wave-uniform, exact).
// Exact-score semantics unchanged from R8-R12: sequential-c fmaf dot,
// pairwise-8 sums, _rn combine, lexicographic (se,k) u64 atomicMin.

#define KNUM 512
#define CDIM 64
#define MPB  64

typedef __attribute__((ext_vector_type(8))) short bf16x8;
typedef __attribute__((ext_vector_type(4))) float f32x4;

__device__ __forceinline__ unsigned f2bf(float f) {   // RNE f32->bf16
    unsigned u = __float_as_uint(f);
    return (u + 0x7FFFu + ((u >> 16) & 1u)) >> 16;
}
__device__ __forceinline__ unsigned ordf(float f) {   // total-order encode
    unsigned u = __float_as_uint(f);
    return u ^ ((unsigned)(((int)u) >> 31) | 0x80000000u);
}
__device__ __forceinline__ float ordinv(unsigned u) {
    unsigned fb = (u & 0x80000000u) ? (u ^ 0x80000000u) : ~u;
    return __uint_as_float(fb);
}

__device__ __forceinline__ float xsq_pairwise8(const float* xr)   // np order
{
    float r[8];
    {
        const float4 a = *(const float4*)&xr[0];
        const float4 c = *(const float4*)&xr[4];
        r[0] = __fmul_rn(a.x, a.x); r[1] = __fmul_rn(a.y, a.y);
        r[2] = __fmul_rn(a.z, a.z); r[3] = __fmul_rn(a.w, a.w);
        r[4] = __fmul_rn(c.x, c.x); r[5] = __fmul_rn(c.y, c.y);
        r[6] = __fmul_rn(c.z, c.z); r[7] = __fmul_rn(c.w, c.w);
    }
    #pragma unroll
    for (int i = 1; i < 8; ++i) {
        const float4 a = *(const float4*)&xr[8 * i];
        const float4 c = *(const float4*)&xr[8 * i + 4];
        r[0] = __fadd_rn(r[0], __fmul_rn(a.x, a.x));
        r[1] = __fadd_rn(r[1], __fmul_rn(a.y, a.y));
        r[2] = __fadd_rn(r[2], __fmul_rn(a.z, a.z));
        r[3] = __fadd_rn(r[3], __fmul_rn(a.w, a.w));
        r[4] = __fadd_rn(r[4], __fmul_rn(c.x, c.x));
        r[5] = __fadd_rn(r[5], __fmul_rn(c.y, c.y));
        r[6] = __fadd_rn(r[6], __fmul_rn(c.z, c.z));
        r[7] = __fadd_rn(r[7], __fmul_rn(c.w, c.w));
    }
    return __fadd_rn(
        __fadd_rn(__fadd_rn(r[0], r[1]), __fadd_rn(r[2], r[3])),
        __fadd_rn(__fadd_rn(r[4], r[5]), __fadd_rn(r[6], r[7])));
}

__global__ __launch_bounds__(64) void vq_prep(const float* __restrict__ emb,
                                              float* __restrict__ e_sq,
                                              unsigned* __restrict__ ebf)
{
    const int k = blockIdx.x * 64 + threadIdx.x;
    const float* e = emb + k * CDIM;
    float4 f[16];
    #pragma unroll
    for (int i = 0; i < 16; ++i) f[i] = ((const float4*)e)[i];

    float r[8];
    r[0] = __fmul_rn(f[0].x, f[0].x); r[1] = __fmul_rn(f[0].y, f[0].y);
    r[2] = __fmul_rn(f[0].z, f[0].z); r[3] = __fmul_rn(f[0].w, f[0].w);
    r[4] = __fmul_rn(f[1].x, f[1].x); r[5] = __fmul_rn(f[1].y, f[1].y);
    r[6] = __fmul_rn(f[1].z, f[1].z); r[7] = __fmul_rn(f[1].w, f[1].w);
    #pragma unroll
    for (int i = 1; i < 8; ++i) {
        const float4 a = f[2 * i], c = f[2 * i + 1];
        r[0] = __fadd_rn(r[0], __fmul_rn(a.x, a.x));
        r[1] = __fadd_rn(r[1], __fmul_rn(a.y, a.y));
        r[2] = __fadd_rn(r[2], __fmul_rn(a.z, a.z));
        r[3] = __fadd_rn(r[3], __fmul_rn(a.w, a.w));
        r[4] = __fadd_rn(r[4], __fmul_rn(c.x, c.x));
        r[5] = __fadd_rn(r[5], __fmul_rn(c.y, c.y));
        r[6] = __fadd_rn(r[6], __fmul_rn(c.z, c.z));
        r[7] = __fadd_rn(r[7], __fmul_rn(c.w, c.w));
    }
    e_sq[k] = __fadd_rn(
        __fadd_rn(__fadd_rn(r[0], r[1]), __fadd_rn(r[2], r[3])),
        __fadd_rn(__fadd_rn(r[4], r[5]), __fadd_rn(r[6], r[7])));

    // bf16(-2e): exact power-of-2 scale, products are exactly -2x original
    unsigned buf[32];
    #pragma unroll
    for (int i = 0; i < 16; ++i) {
        buf[2 * i]     = f2bf(__fmul_rn(-2.0f, f[i].x))
                       | (f2bf(__fmul_rn(-2.0f, f[i].y)) << 16);
        buf[2 * i + 1] = f2bf(__fmul_rn(-2.0f, f[i].z))
                       | (f2bf(__fmul_rn(-2.0f, f[i].w)) << 16);
    }
    uint4* dst = (uint4*)(ebf + k * 32);
    #pragma unroll
    for (int i = 0; i < 8; ++i) dst[i] = ((const uint4*)buf)[i];
}

__global__ __launch_bounds__(512, 6) void vq_main(const float* __restrict__ x,
                                                  const float* __restrict__ emb,
                                                  const float* __restrict__ e_sq,
                                                  const unsigned* __restrict__ ebf,
                                                  float* __restrict__ out)
{
    __shared__ float    xt[MPB][68];           // 17408 B exact x
    __shared__ _Float16 xbf[MPB][72];          //  9216 B bf16 x (B-frags)
    __shared__ float    axp[MPB][10];          //  2560 B |x| partials
    __shared__ float    margl[MPB];            //   256 B per-pixel margin
    __shared__ float    xsql[MPB];             //   256 B per-pixel ||x||^2
    __shared__ float    lesq[KNUM];            //  2048 B e_sq copy
    __shared__ unsigned pthr[MPB];             //   256 B ordered screen min
    __shared__ unsigned long long bestpk[MPB]; //   512 B

    const int t    = threadIdx.x;
    const int pix0 = blockIdx.x * MPB;
    const int b    = pix0 >> 12;
    const int hw0  = pix0 & 4095;
    const float* xb = x + ((size_t)b << 18) + hw0;

    const int l    = t & 63;
    const int w    = __builtin_amdgcn_readfirstlane(t >> 6);  // uniform wave id
    const int i15  = l & 15, quad = l >> 4;
    const int nbase = w * 64;

    // ---- stage x (HBM/L3, longest latency first) ----
    {
        const float* xp = xb + ((size_t)(8 * w) << 12) + l;
        float v[8];
        #pragma unroll
        for (int j = 0; j < 8; ++j) v[j] = xp[(size_t)j << 12];

        lesq[t] = e_sq[t];                     // KNUM == blockDim
        if (t < MPB) { pthr[t] = 0xFFFFFFFFu; bestpk[t] = ~0ull; }

        *(float4*)&xt[l][8 * w]     = make_float4(v[0], v[1], v[2], v[3]);
        *(float4*)&xt[l][8 * w + 4] = make_float4(v[4], v[5], v[6], v[7]);
        uint4 dp;
        dp.x = f2bf(v[0]) | (f2bf(v[1]) << 16);
        dp.y = f2bf(v[2]) | (f2bf(v[3]) << 16);
        dp.z = f2bf(v[4]) | (f2bf(v[5]) << 16);
        dp.w = f2bf(v[6]) | (f2bf(v[7]) << 16);
        *(uint4*)&xbf[l][8 * w] = dp;
        axp[l][w] = ((fabsf(v[0]) + fabsf(v[1])) + (fabsf(v[2]) + fabsf(v[3])))
                  + ((fabsf(v[4]) + fabsf(v[5])) + (fabsf(v[6]) + fabsf(v[7])));
    }
    __syncthreads();                           // B1

    // ---- wave 0: per-pixel margin; waves 4-7: exact ||x||^2 ----
    if (t < MPB) {
        const float ax = ((axp[t][0] + axp[t][1]) + (axp[t][2] + axp[t][3]))
                       + ((axp[t][4] + axp[t][5]) + (axp[t][6] + axp[t][7]));
        margl[t] = fmaf(4.0e-5f, ax, 5.0e-4f);
    }
    if (w >= 4 && l < 16) {                    // 2-way bank alias = free
        const int p = (w - 4) * 16 + l;
        xsql[p] = xsq_pairwise8(xt[p]);
    }

    // ---- pass 1: MFMA screen, ef streamed from L2, keep cell mins only ----
    float mm4[4][4];                           // [mt][nt]
    #pragma unroll
    for (int mt = 0; mt < 4; ++mt) {
        const char* ep = (const char*)ebf
            + (size_t)(nbase + mt * 16 + i15) * 128 + quad * 16;
        const bf16x8 ef0 = *(const bf16x8*)(ep);
        const bf16x8 ef1 = *(const bf16x8*)(ep + 64);
        #pragma unroll
        for (int nt = 0; nt < 4; ++nt) {
            const bf16x8 xf0 = *(const bf16x8*)&xbf[nt * 16 + i15][quad * 8];
            const bf16x8 xf1 = *(const bf16x8*)&xbf[nt * 16 + i15][quad * 8 + 32];
            f32x4 acc = *(const f32x4*)&lesq[nbase + mt * 16 + quad * 4];
            acc = __builtin_amdgcn_mfma_f32_16x16x32_bf16(ef0, xf0, acc, 0, 0, 0);
            acc = __builtin_amdgcn_mfma_f32_16x16x32_bf16(ef1, xf1, acc, 0, 0, 0);
            mm4[mt][nt] = fminf(fminf(acc[0], acc[1]), fminf(acc[2], acc[3]));
        }
    }
    // per-pixel min over this wave's 64 codes: 3 fmin + 2 shfl per nt
    #pragma unroll
    for (int nt = 0; nt < 4; ++nt) {
        float mv = fminf(fminf(mm4[0][nt], mm4[1][nt]),
                         fminf(mm4[2][nt], mm4[3][nt]));
        mv = fminf(mv, __shfl_xor(mv, 16));
        mv = fminf(mv, __shfl_xor(mv, 32));
        if (quad == 0) atomicMin(&pthr[nt * 16 + i15], ordf(mv));
    }
    __syncthreads();                           // B2

    // ---- pass 2: recompute gated tiles, per-element detect, serial rescore ----
    {
        float tr[4];
        #pragma unroll
        for (int nt = 0; nt < 4; ++nt)
            tr[nt] = __fadd_rn(ordinv(pthr[nt * 16 + i15]),
                               margl[nt * 16 + i15]);

        unsigned long long m = 0;
        #pragma unroll
        for (int mt = 0; mt < 4; ++mt) {
            // wave-uniform gate: any lane's cell min under threshold?
            bool any = false;
            #pragma unroll
            for (int nt = 0; nt < 4; ++nt)
                any = any || (mm4[mt][nt] < tr[nt]);
            if (!__any(any)) continue;

            const char* ep = (const char*)ebf
                + (size_t)(nbase + mt * 16 + i15) * 128 + quad * 16;
            const bf16x8 ef0 = *(const bf16x8*)(ep);
            const bf16x8 ef1 = *(const bf16x8*)(ep + 64);
            #pragma unroll
            for (int nt = 0; nt < 4; ++nt) {
                const bf16x8 xf0 = *(const bf16x8*)&xbf[nt * 16 + i15][quad * 8];
                const bf16x8 xf1 = *(const bf16x8*)&xbf[nt * 16 + i15][quad * 8 + 32];
                f32x4 acc = *(const f32x4*)&lesq[nbase + mt * 16 + quad * 4];
                acc = __builtin_amdgcn_mfma_f32_16x16x32_bf16(ef0, xf0, acc, 0, 0, 0);
                acc = __builtin_amdgcn_mfma_f32_16x16x32_bf16(ef1, xf1, acc, 0, 0, 0);
                #pragma unroll
                for (int r = 0; r < 4; ++r)
                    if (acc[r] < tr[nt])       // rare
                        m |= 1ull << (mt * 16 + nt * 4 + r);
            }
        }

        while (m) {                            // serial rescore (R12 body)
            const int bit = __builtin_ctzll(m);
            m &= m - 1;
            const int mt = bit >> 4, nt = (bit >> 2) & 3, r = bit & 3;
            const int p2 = nt * 16 + i15;                    // pixel
            const int k  = nbase + mt * 16 + quad * 4 + r;   // code
            const float xs = xsql[p2];
            const float* er = emb + (size_t)k * CDIM;
            float d = 0.f;
            #pragma unroll
            for (int c4 = 0; c4 < 16; ++c4) {  // sequential-c fmaf = np order
                const float4 xv = *(const float4*)&xt[p2][4 * c4];
                const float4 ev = *(const float4*)&er[4 * c4];
                d = fmaf(xv.x, ev.x, d);
                d = fmaf(xv.y, ev.y, d);
                d = fmaf(xv.z, ev.z, d);
                d = fmaf(xv.w, ev.w, d);
            }
            const float se = __fsub_rn(__fadd_rn(xs, lesq[k]),
                                       __fmul_rn(2.0f, d));
            const unsigned long long pkd =
                ((unsigned long long)ordf(se) << 32) | (unsigned)k;
            atomicMin(&bestpk[p2], pkd);       // lexicographic (se, k)
        }
    }
    __syncthreads();                           // B3

    // ---- gather winning emb row (bit-exact) -> [B,C,H,W] ----
    {
        const int wi = (int)(bestpk[l] & 0xFFFFu);
        const float* ew = emb + (size_t)wi * CDIM + 8 * w;
        const float4 e0 = *(const float4*)ew;
        const float4 e1 = *(const float4*)(ew + 4);
        float* ob = out + ((size_t)b << 18) + (((size_t)(8 * w)) << 12) + hw0 + l;
        ob[(size_t)0 << 12] = e0.x;
        ob[(size_t)1 << 12] = e0.y;
        ob[(size_t)2 << 12] = e0.z;
        ob[(size_t)3 << 12] = e0.w;
        ob[(size_t)4 << 12] = e1.x;
        ob[(size_t)5 << 12] = e1.y;
        ob[(size_t)6 << 12] = e1.z;
        ob[(size_t)7 << 12] = e1.w;
    }
}

extern "C" void kernel_launch(void* const* d_in, const int* in_sizes, int n_in,
                              void* d_out, int out_size, void* d_ws, size_t ws_size,
                              hipStream_t stream)
{
    const float* x   = (const float*)d_in[0];
    const float* emb = (const float*)d_in[1];
    float* out  = (float*)d_out;
    float*    e_sq = (float*)d_ws;                 // 2 KB
    unsigned* ebf  = (unsigned*)d_ws + KNUM;       // 64 KB bf16(-2e)

    hipLaunchKernelGGL(vq_prep, dim3(KNUM / 64), dim3(64), 0, stream, emb, e_sq, ebf);
    const int nblocks = (32 * 64 * 64) / MPB;      // 2048
    hipLaunchKernelGGL(vq_main, dim3(nblocks), dim3(512), 0, stream,
                       x, emb, e_sq, ebf, out);
}

// Round 6
// 124.295 us; speedup vs baseline: 1.3388x; 1.2582x over previous
//
#include <hip/hip_runtime.h>

// VectorQuantizer: x [32,64,64,64] f32, emb [512,64] f32 -> out [32,64,64,64] f32
// R16: barrier-minimal R12. R14/R15 proved the reg-cap path spills (compiler
// won't fit the screen under 85 regs; WRITE_SIZE 143-180MB scratch). Revert to
// the spill-free 128-reg band ((512,4), scores held) and remove the B2 global
// sync instead:
//  - pthr is monotone-decreasing under atomicMin -> stale reads give a LARGER
//    threshold -> candidate SUPERSET -> exact rescore still decides; bestpk
//    atomicMin is order-independent -> deterministic output, absmax==0.
//    Each wave: screen -> atomicMin(pthr) -> threadfence_block -> read pthr
//    (stale-safe) -> detect -> rescore. 2 barriers total (B1, B3).
//  - margin per-lane from axp + 1 shfl (margl LDS + wave-0 job deleted)
//  - rescore computes xsq INLINE merged into the dot pass over xt[p2]
//    (identical pairwise-8 square order + identical sequential fmaf order ->
//    bit-exact; halves rescore LDS reads; xsql + waves4-7 job deleted)
// Exact-score semantics unchanged from R8-R12: sequential-c fmaf dot,
// pairwise-8 sums, _rn combine, lexicographic (se,k) u64 atomicMin.

#define KNUM 512
#define CDIM 64
#define MPB  64

typedef __attribute__((ext_vector_type(8))) short bf16x8;
typedef __attribute__((ext_vector_type(4))) float f32x4;

__device__ __forceinline__ unsigned f2bf(float f) {   // RNE f32->bf16
    unsigned u = __float_as_uint(f);
    return (u + 0x7FFFu + ((u >> 16) & 1u)) >> 16;
}
__device__ __forceinline__ unsigned ordf(float f) {   // total-order encode
    unsigned u = __float_as_uint(f);
    return u ^ ((unsigned)(((int)u) >> 31) | 0x80000000u);
}
__device__ __forceinline__ float ordinv(unsigned u) {
    unsigned fb = (u & 0x80000000u) ? (u ^ 0x80000000u) : ~u;
    return __uint_as_float(fb);
}

__device__ __forceinline__ float xsq_pairwise8(const float* xr)   // np order
{
    float r[8];
    {
        const float4 a = *(const float4*)&xr[0];
        const float4 c = *(const float4*)&xr[4];
        r[0] = __fmul_rn(a.x, a.x); r[1] = __fmul_rn(a.y, a.y);
        r[2] = __fmul_rn(a.z, a.z); r[3] = __fmul_rn(a.w, a.w);
        r[4] = __fmul_rn(c.x, c.x); r[5] = __fmul_rn(c.y, c.y);
        r[6] = __fmul_rn(c.z, c.z); r[7] = __fmul_rn(c.w, c.w);
    }
    #pragma unroll
    for (int i = 1; i < 8; ++i) {
        const float4 a = *(const float4*)&xr[8 * i];
        const float4 c = *(const float4*)&xr[8 * i + 4];
        r[0] = __fadd_rn(r[0], __fmul_rn(a.x, a.x));
        r[1] = __fadd_rn(r[1], __fmul_rn(a.y, a.y));
        r[2] = __fadd_rn(r[2], __fmul_rn(a.z, a.z));
        r[3] = __fadd_rn(r[3], __fmul_rn(a.w, a.w));
        r[4] = __fadd_rn(r[4], __fmul_rn(c.x, c.x));
        r[5] = __fadd_rn(r[5], __fmul_rn(c.y, c.y));
        r[6] = __fadd_rn(r[6], __fmul_rn(c.z, c.z));
        r[7] = __fadd_rn(r[7], __fmul_rn(c.w, c.w));
    }
    return __fadd_rn(
        __fadd_rn(__fadd_rn(r[0], r[1]), __fadd_rn(r[2], r[3])),
        __fadd_rn(__fadd_rn(r[4], r[5]), __fadd_rn(r[6], r[7])));
}

__global__ __launch_bounds__(64) void vq_prep(const float* __restrict__ emb,
                                              float* __restrict__ e_sq,
                                              unsigned* __restrict__ ebf)
{
    const int k = blockIdx.x * 64 + threadIdx.x;
    const float* e = emb + k * CDIM;
    float4 f[16];
    #pragma unroll
    for (int i = 0; i < 16; ++i) f[i] = ((const float4*)e)[i];

    float r[8];
    r[0] = __fmul_rn(f[0].x, f[0].x); r[1] = __fmul_rn(f[0].y, f[0].y);
    r[2] = __fmul_rn(f[0].z, f[0].z); r[3] = __fmul_rn(f[0].w, f[0].w);
    r[4] = __fmul_rn(f[1].x, f[1].x); r[5] = __fmul_rn(f[1].y, f[1].y);
    r[6] = __fmul_rn(f[1].z, f[1].z); r[7] = __fmul_rn(f[1].w, f[1].w);
    #pragma unroll
    for (int i = 1; i < 8; ++i) {
        const float4 a = f[2 * i], c = f[2 * i + 1];
        r[0] = __fadd_rn(r[0], __fmul_rn(a.x, a.x));
        r[1] = __fadd_rn(r[1], __fmul_rn(a.y, a.y));
        r[2] = __fadd_rn(r[2], __fmul_rn(a.z, a.z));
        r[3] = __fadd_rn(r[3], __fmul_rn(a.w, a.w));
        r[4] = __fadd_rn(r[4], __fmul_rn(c.x, c.x));
        r[5] = __fadd_rn(r[5], __fmul_rn(c.y, c.y));
        r[6] = __fadd_rn(r[6], __fmul_rn(c.z, c.z));
        r[7] = __fadd_rn(r[7], __fmul_rn(c.w, c.w));
    }
    e_sq[k] = __fadd_rn(
        __fadd_rn(__fadd_rn(r[0], r[1]), __fadd_rn(r[2], r[3])),
        __fadd_rn(__fadd_rn(r[4], r[5]), __fadd_rn(r[6], r[7])));

    // bf16(-2e): exact power-of-2 scale, products are exactly -2x original
    unsigned buf[32];
    #pragma unroll
    for (int i = 0; i < 16; ++i) {
        buf[2 * i]     = f2bf(__fmul_rn(-2.0f, f[i].x))
                       | (f2bf(__fmul_rn(-2.0f, f[i].y)) << 16);
        buf[2 * i + 1] = f2bf(__fmul_rn(-2.0f, f[i].z))
                       | (f2bf(__fmul_rn(-2.0f, f[i].w)) << 16);
    }
    uint4* dst = (uint4*)(ebf + k * 32);
    #pragma unroll
    for (int i = 0; i < 8; ++i) dst[i] = ((const uint4*)buf)[i];
}

__global__ __launch_bounds__(512, 4) void vq_main(const float* __restrict__ x,
                                                  const float* __restrict__ emb,
                                                  const float* __restrict__ e_sq,
                                                  const unsigned* __restrict__ ebf,
                                                  float* __restrict__ out)
{
    __shared__ float    xt[MPB][68];           // 17408 B exact x
    __shared__ _Float16 xbf[MPB][72];          //  9216 B bf16 x (B-frags)
    __shared__ float    axp[MPB][10];          //  2560 B |x| partials
    __shared__ float    lesq[KNUM];            //  2048 B e_sq copy
    __shared__ unsigned pthr[MPB];             //   256 B ordered screen min
    __shared__ unsigned long long bestpk[MPB]; //   512 B

    const int t    = threadIdx.x;
    const int pix0 = blockIdx.x * MPB;
    const int b    = pix0 >> 12;
    const int hw0  = pix0 & 4095;
    const float* xb = x + ((size_t)b << 18) + hw0;

    const int l    = t & 63;
    const int w    = __builtin_amdgcn_readfirstlane(t >> 6);  // uniform wave id
    const int i15  = l & 15, quad = l >> 4;
    const int nbase = w * 64;

    // ---- stage x (HBM/L3, longest latency first) ----
    {
        const float* xp = xb + ((size_t)(8 * w) << 12) + l;
        float v[8];
        #pragma unroll
        for (int j = 0; j < 8; ++j) v[j] = xp[(size_t)j << 12];

        lesq[t] = e_sq[t];                     // KNUM == blockDim
        if (t < MPB) { pthr[t] = 0xFFFFFFFFu; bestpk[t] = ~0ull; }

        *(float4*)&xt[l][8 * w]     = make_float4(v[0], v[1], v[2], v[3]);
        *(float4*)&xt[l][8 * w + 4] = make_float4(v[4], v[5], v[6], v[7]);
        uint4 dp;
        dp.x = f2bf(v[0]) | (f2bf(v[1]) << 16);
        dp.y = f2bf(v[2]) | (f2bf(v[3]) << 16);
        dp.z = f2bf(v[4]) | (f2bf(v[5]) << 16);
        dp.w = f2bf(v[6]) | (f2bf(v[7]) << 16);
        *(uint4*)&xbf[l][8 * w] = dp;
        axp[l][w] = ((fabsf(v[0]) + fabsf(v[1])) + (fabsf(v[2]) + fabsf(v[3])))
                  + ((fabsf(v[4]) + fabsf(v[5])) + (fabsf(v[6]) + fabsf(v[7])));
    }
    __syncthreads();                           // B1 (the only pre-gather barrier)

    // ---- per-lane margin for own pixel l (every wave; no cross-wave job) ----
    float margme;
    {
        const float2 g0 = *(const float2*)&axp[l][0];
        const float2 g1 = *(const float2*)&axp[l][2];
        const float2 g2 = *(const float2*)&axp[l][4];
        const float2 g3 = *(const float2*)&axp[l][6];
        const float ax = ((g0.x + g0.y) + (g1.x + g1.y))
                       + ((g2.x + g2.y) + (g3.x + g3.y));
        margme = fmaf(4.0e-5f, ax, 5.0e-4f);
    }

    // ---- prefetch code A-frags (bf16(-2e)) from L2 ----
    bf16x8 efr[4][2];
    #pragma unroll
    for (int mt = 0; mt < 4; ++mt)
        #pragma unroll
        for (int kc = 0; kc < 2; ++kc)
            efr[mt][kc] = *(const bf16x8*)((const char*)ebf
                + (size_t)(nbase + mt * 16 + i15) * 128 + kc * 64 + quad * 16);

    // ---- MFMA screen: D[code][pixel] = e_sq[code] + (-2e).x, scores held ----
    float s[4][4][4];                          // [mt][nt][r], code-major
    #pragma unroll
    for (int nt = 0; nt < 4; ++nt) {
        const bf16x8 xf0 = *(const bf16x8*)&xbf[nt * 16 + i15][quad * 8];
        const bf16x8 xf1 = *(const bf16x8*)&xbf[nt * 16 + i15][quad * 8 + 32];
        #pragma unroll
        for (int mt = 0; mt < 4; ++mt) {
            f32x4 acc = *(const f32x4*)&lesq[nbase + mt * 16 + quad * 4];
            acc = __builtin_amdgcn_mfma_f32_16x16x32_bf16(efr[mt][0], xf0, acc, 0, 0, 0);
            acc = __builtin_amdgcn_mfma_f32_16x16x32_bf16(efr[mt][1], xf1, acc, 0, 0, 0);
            #pragma unroll
            for (int r = 0; r < 4; ++r)        // code=quad*4+r(+16mt), pixel=i15(+16nt)
                s[mt][nt][r] = acc[r];
        }
    }
    // per-pixel min over this wave's 64 codes -> shared monotone pthr
    #pragma unroll
    for (int nt = 0; nt < 4; ++nt) {
        float mv = fminf(fminf(fminf(s[0][nt][0], s[0][nt][1]),
                               fminf(s[0][nt][2], s[0][nt][3])),
                         fminf(fminf(s[1][nt][0], s[1][nt][1]),
                               fminf(s[1][nt][2], s[1][nt][3])));
        mv = fminf(mv, fminf(fminf(fminf(s[2][nt][0], s[2][nt][1]),
                                   fminf(s[2][nt][2], s[2][nt][3])),
                             fminf(fminf(s[3][nt][0], s[3][nt][1]),
                                   fminf(s[3][nt][2], s[3][nt][3]))));
        mv = fminf(mv, __shfl_xor(mv, 16));
        mv = fminf(mv, __shfl_xor(mv, 32));
        if (quad == 0) atomicMin(&pthr[nt * 16 + i15], ordf(mv));
    }
    __threadfence_block();                     // order own atomics before reads

    // ---- detect vs STALE-SAFE shared threshold (pthr only decreases ->
    //      any read gives a superset of the global-threshold candidates) ----
    {
        float tr[4];
        #pragma unroll
        for (int nt = 0; nt < 4; ++nt) {
            const float mrow = __shfl(margme, nt * 16 + i15);
            tr[nt] = __fadd_rn(ordinv(pthr[nt * 16 + i15]), mrow);
        }

        unsigned long long m = 0;
        #pragma unroll
        for (int mt = 0; mt < 4; ++mt)
            #pragma unroll
            for (int nt = 0; nt < 4; ++nt)
                #pragma unroll
                for (int r = 0; r < 4; ++r)
                    if (s[mt][nt][r] < tr[nt])               // rare
                        m |= 1ull << (mt * 16 + nt * 4 + r);

        while (m) {                            // serial exact rescore
            const int bit = __builtin_ctzll(m);
            m &= m - 1;
            const int mt = bit >> 4, nt = (bit >> 2) & 3, r = bit & 3;
            const int p2 = nt * 16 + i15;                    // pixel
            const int k  = nbase + mt * 16 + quad * 4 + r;   // code
            const float* xr = &xt[p2][0];
            const float* er = emb + (size_t)k * CDIM;
            // merged single pass: xsq (pairwise-8 order) + dot (sequential
            // fmaf order) -- both bit-identical to the separate np passes
            float q[8], d;
            {
                const float4 a = *(const float4*)&xr[0];
                const float4 c = *(const float4*)&xr[4];
                const float4 ea = *(const float4*)&er[0];
                const float4 ec = *(const float4*)&er[4];
                q[0] = __fmul_rn(a.x, a.x); q[1] = __fmul_rn(a.y, a.y);
                q[2] = __fmul_rn(a.z, a.z); q[3] = __fmul_rn(a.w, a.w);
                q[4] = __fmul_rn(c.x, c.x); q[5] = __fmul_rn(c.y, c.y);
                q[6] = __fmul_rn(c.z, c.z); q[7] = __fmul_rn(c.w, c.w);
                d = fmaf(a.x, ea.x, 0.f);
                d = fmaf(a.y, ea.y, d);
                d = fmaf(a.z, ea.z, d);
                d = fmaf(a.w, ea.w, d);
                d = fmaf(c.x, ec.x, d);
                d = fmaf(c.y, ec.y, d);
                d = fmaf(c.z, ec.z, d);
                d = fmaf(c.w, ec.w, d);
            }
            #pragma unroll
            for (int i = 1; i < 8; ++i) {
                const float4 a = *(const float4*)&xr[8 * i];
                const float4 c = *(const float4*)&xr[8 * i + 4];
                const float4 ea = *(const float4*)&er[8 * i];
                const float4 ec = *(const float4*)&er[8 * i + 4];
                q[0] = __fadd_rn(q[0], __fmul_rn(a.x, a.x));
                q[1] = __fadd_rn(q[1], __fmul_rn(a.y, a.y));
                q[2] = __fadd_rn(q[2], __fmul_rn(a.z, a.z));
                q[3] = __fadd_rn(q[3], __fmul_rn(a.w, a.w));
                q[4] = __fadd_rn(q[4], __fmul_rn(c.x, c.x));
                q[5] = __fadd_rn(q[5], __fmul_rn(c.y, c.y));
                q[6] = __fadd_rn(q[6], __fmul_rn(c.z, c.z));
                q[7] = __fadd_rn(q[7], __fmul_rn(c.w, c.w));
                d = fmaf(a.x, ea.x, d);
                d = fmaf(a.y, ea.y, d);
                d = fmaf(a.z, ea.z, d);
                d = fmaf(a.w, ea.w, d);
                d = fmaf(c.x, ec.x, d);
                d = fmaf(c.y, ec.y, d);
                d = fmaf(c.z, ec.z, d);
                d = fmaf(c.w, ec.w, d);
            }
            const float xs = __fadd_rn(
                __fadd_rn(__fadd_rn(q[0], q[1]), __fadd_rn(q[2], q[3])),
                __fadd_rn(__fadd_rn(q[4], q[5]), __fadd_rn(q[6], q[7])));
            const float se = __fsub_rn(__fadd_rn(xs, lesq[k]),
                                       __fmul_rn(2.0f, d));
            const unsigned long long pkd =
                ((unsigned long long)ordf(se) << 32) | (unsigned)k;
            atomicMin(&bestpk[p2], pkd);       // lexicographic (se, k)
        }
    }
    __syncthreads();                           // B3: all rescores visible

    // ---- gather winning emb row (bit-exact) -> [B,C,H,W] ----
    {
        const int wi = (int)(bestpk[l] & 0xFFFFu);
        const float* ew = emb + (size_t)wi * CDIM + 8 * w;
        const float4 e0 = *(const float4*)ew;
        const float4 e1 = *(const float4*)(ew + 4);
        float* ob = out + ((size_t)b << 18) + (((size_t)(8 * w)) << 12) + hw0 + l;
        ob[(size_t)0 << 12] = e0.x;
        ob[(size_t)1 << 12] = e0.y;
        ob[(size_t)2 << 12] = e0.z;
        ob[(size_t)3 << 12] = e0.w;
        ob[(size_t)4 << 12] = e1.x;
        ob[(size_t)5 << 12] = e1.y;
        ob[(size_t)6 << 12] = e1.z;
        ob[(size_t)7 << 12] = e1.w;
    }
}

extern "C" void kernel_launch(void* const* d_in, const int* in_sizes, int n_in,
                              void* d_out, int out_size, void* d_ws, size_t ws_size,
                              hipStream_t stream)
{
    const float* x   = (const float*)d_in[0];
    const float* emb = (const float*)d_in[1];
    float* out  = (float*)d_out;
    float*    e_sq = (float*)d_ws;                 // 2 KB
    unsigned* ebf  = (unsigned*)d_ws + KNUM;       // 64 KB bf16(-2e)

    hipLaunchKernelGGL(vq_prep, dim3(KNUM / 64), dim3(64), 0, stream, emb, e_sq, ebf);
    const int nblocks = (32 * 64 * 64) / MPB;      // 2048
    hipLaunchKernelGGL(vq_main, dim3(nblocks), dim3(512), 0, stream,
                       x, emb, e_sq, ebf, out);
}